// Round 1
// baseline (161.814 us; speedup 1.0000x reference)
//
#include <hip/hip_runtime.h>
#include <math.h>

// Problem constants (from reference):
// N=65536 nodes, F=256 feat, E=16 experts, D=256 emb, H=512 hidden, G=256 graphs
#define FF 256
#define EE 16
#define DD 256
#define HH 512
#define GG 256

// One block per graph. Only the G=256 gathered nodes matter — everything for
// the other 65280 nodes in the reference is dead code.
__global__ __launch_bounds__(256) void fused_graph_kernel(
    const float* __restrict__ node_fea,   // [N,F]
    const float* __restrict__ masks,      // [N,F]
    const int*   __restrict__ node_type,  // [N]
    const int*   __restrict__ g_node_id,  // [G]
    const int*   __restrict__ label,      // [G]
    const float* __restrict__ W_emb,      // [E,F,D]
    const float* __restrict__ b_emb,      // [E,D]
    const float* __restrict__ W_hid,      // [D,H]
    const float* __restrict__ b_hid,      // [H]
    const float* __restrict__ W_out,      // [H,2]
    const float* __restrict__ b_out,      // [2]
    float* __restrict__ probs_out,        // [G,2]  (= d_out[0..511])
    float* __restrict__ loss_ws)          // [G]    (workspace)
{
    __shared__ float xm[FF];
    __shared__ float emb[DD];
    __shared__ float red0[4];
    __shared__ float red1[4];

    const int g = blockIdx.x;
    const int t = threadIdx.x;
    const int n = g_node_id[g];
    const int e = node_type[n];

    // ---- stage 1: masked features for this graph's node ----
    {
        size_t base = (size_t)n * FF + t;
        xm[t] = node_fea[base] * masks[base];
    }
    __syncthreads();

    // ---- stage 2: emb[t] = b_emb[e][t] + sum_f xm[f] * W_emb[e][f][t] ----
    // Thread t owns output column t; per-f the wave reads 64 consecutive
    // floats of W_emb -> coalesced.  xm[f] is an LDS broadcast (free).
    {
        const float* __restrict__ W = W_emb + (size_t)e * FF * DD + t;
        float acc = b_emb[e * DD + t];
        #pragma unroll 8
        for (int f = 0; f < FF; ++f) {
            acc = fmaf(xm[f], W[(size_t)f * DD], acc);
        }
        emb[t] = acc;
    }
    __syncthreads();

    // ---- stage 3: h_j for j=t and j=t+256, fused straight into W_out dot ----
    // h never materialized: z0 = sum_j h_j*W_out[j][0], z1 = sum_j h_j*W_out[j][1]
    float z0p, z1p;
    {
        const float* __restrict__ Wh0 = W_hid + t;
        const float* __restrict__ Wh1 = W_hid + t + 256;
        float h0 = b_hid[t];
        float h1 = b_hid[t + 256];
        #pragma unroll 8
        for (int d = 0; d < DD; ++d) {
            float ed = emb[d];
            h0 = fmaf(ed, Wh0[(size_t)d * HH], h0);
            h1 = fmaf(ed, Wh1[(size_t)d * HH], h1);
        }
        z0p = h0 * W_out[2 * t + 0] + h1 * W_out[2 * (t + 256) + 0];
        z1p = h0 * W_out[2 * t + 1] + h1 * W_out[2 * (t + 256) + 1];
    }

    // ---- block reduce z0p, z1p across 256 threads (4 waves) ----
    for (int off = 32; off > 0; off >>= 1) {
        z0p += __shfl_down(z0p, off, 64);
        z1p += __shfl_down(z1p, off, 64);
    }
    if ((t & 63) == 0) { red0[t >> 6] = z0p; red1[t >> 6] = z1p; }
    __syncthreads();

    if (t == 0) {
        float z0 = b_out[0] + red0[0] + red0[1] + red0[2] + red0[3];
        float z1 = b_out[1] + red1[0] + red1[1] + red1[2] + red1[3];
        // probs = softmax(z)
        float m  = fmaxf(z0, z1);
        float e0 = expf(z0 - m), e1 = expf(z1 - m);
        float inv = 1.0f / (e0 + e1);
        float p0 = e0 * inv, p1 = e1 * inv;
        probs_out[2 * g + 0] = p0;
        probs_out[2 * g + 1] = p1;
        // loss term = -(log_softmax(probs)[label]) = lse(p) - p[label]
        float mp  = fmaxf(p0, p1);
        float lse = mp + logf(expf(p0 - mp) + expf(p1 - mp));
        float pl  = (label[g] == 0) ? p0 : p1;
        loss_ws[g] = lse - pl;
    }
}

// Deterministic single-block sum of the 256 per-graph loss terms.
__global__ __launch_bounds__(256) void loss_reduce_kernel(
    const float* __restrict__ loss_ws, float* __restrict__ out)
{
    __shared__ float red[4];
    int t = threadIdx.x;
    float v = loss_ws[t];
    for (int off = 32; off > 0; off >>= 1) v += __shfl_down(v, off, 64);
    if ((t & 63) == 0) red[t >> 6] = v;
    __syncthreads();
    if (t == 0) out[0] = red[0] + red[1] + red[2] + red[3];
}

extern "C" void kernel_launch(void* const* d_in, const int* in_sizes, int n_in,
                              void* d_out, int out_size, void* d_ws, size_t ws_size,
                              hipStream_t stream) {
    const float* node_fea  = (const float*)d_in[0];
    const float* masks     = (const float*)d_in[1];
    const int*   node_type = (const int*)  d_in[2];
    const int*   g_node_id = (const int*)  d_in[3];
    const int*   label     = (const int*)  d_in[4];
    const float* W_emb     = (const float*)d_in[5];
    const float* b_emb     = (const float*)d_in[6];
    const float* W_hid     = (const float*)d_in[7];
    const float* b_hid     = (const float*)d_in[8];
    const float* W_out     = (const float*)d_in[9];
    const float* b_out     = (const float*)d_in[10];

    float* out = (float*)d_out;  // [G*2 probs][1 loss] = 513 floats
    float* ws  = (float*)d_ws;   // >= G floats of scratch

    fused_graph_kernel<<<GG, 256, 0, stream>>>(
        node_fea, masks, node_type, g_node_id, label,
        W_emb, b_emb, W_hid, b_hid, W_out, b_out,
        out, ws);

    loss_reduce_kernel<<<1, 256, 0, stream>>>(ws, out + GG * 2);
}

// Round 2
// 151.809 us; speedup vs baseline: 1.0659x; 1.0659x over previous
//
#include <hip/hip_runtime.h>
#include <math.h>

// Problem constants (from reference):
// N=65536 nodes, F=256 feat, E=16 experts, D=256 emb, H=512 hidden, G=256 graphs
#define FF 256
#define EE 16
#define DD 256
#define HH 512
#define GG 256

// One block per graph; only the G=256 gathered nodes matter (rest of the
// reference's N=65536 node computation is dead code past the gather).
//
// Parallelization: 4 waves/block. Each wave owns a 64-wide slice of the
// reduction dim (f for stage 2, d for stage 3); each lane owns 4 consecutive
// output columns via float4 loads (64 lanes x 16 B = 1 KB/instr, fully
// coalesced). Partials combine through LDS. This cuts per-thread load count
// 768 -> 192 and makes every global load a dwordx4 — important because at
// 256 blocks we have 1 wave/SIMD and latency hiding must come from ILP.
__global__ __launch_bounds__(256) void fused_graph_kernel(
    const float* __restrict__ node_fea,   // [N,F]
    const float* __restrict__ masks,      // [N,F]
    const int*   __restrict__ node_type,  // [N]
    const int*   __restrict__ g_node_id,  // [G]
    const int*   __restrict__ label,      // [G]
    const float* __restrict__ W_emb,      // [E,F,D]
    const float* __restrict__ b_emb,      // [E,D]
    const float* __restrict__ W_hid,      // [D,H]
    const float* __restrict__ b_hid,      // [H]
    const float* __restrict__ W_out,      // [H,2]
    const float* __restrict__ b_out,      // [2]
    float* __restrict__ probs_out,        // [G,2]  (= d_out[0..511])
    float* __restrict__ loss_ws)          // [G]    (workspace)
{
    __shared__ __align__(16) float xm[FF];
    __shared__ __align__(16) float part[4][DD];
    __shared__ __align__(16) float emb[DD];
    __shared__ float red0[4];
    __shared__ float red1[4];

    const int g = blockIdx.x;
    const int t = threadIdx.x;
    const int w = t >> 6;   // wave id 0..3
    const int l = t & 63;   // lane   0..63
    const int c = l << 2;   // this lane's 4-column base
    const int n = g_node_id[g];
    const int e = node_type[n];

    // ---- stage 1: masked features for this graph's node ----
    {
        size_t base = (size_t)n * FF + t;
        xm[t] = node_fea[base] * masks[base];
    }
    __syncthreads();

    // ---- stage 2: emb = xm @ W_emb[e] + b_emb[e] ----
    // Wave w reduces f in [64w, 64w+64); lane owns columns c..c+3.
    {
        const float* __restrict__ Wb = W_emb + (size_t)e * FF * DD;
        float4 acc = {0.f, 0.f, 0.f, 0.f};
        #pragma unroll 8
        for (int i = 0; i < 64; ++i) {
            const int f = (w << 6) + i;
            const float s = xm[f];
            const float4 wv = *(const float4*)(Wb + (size_t)f * DD + c);
            acc.x = fmaf(s, wv.x, acc.x);
            acc.y = fmaf(s, wv.y, acc.y);
            acc.z = fmaf(s, wv.z, acc.z);
            acc.w = fmaf(s, wv.w, acc.w);
        }
        *(float4*)&part[w][c] = acc;
    }
    __syncthreads();

    // combine wave partials + bias; thread t owns emb column t
    emb[t] = part[0][t] + part[1][t] + part[2][t] + part[3][t]
           + b_emb[e * DD + t];
    __syncthreads();

    // ---- stage 3: z = W_out^T (W_hid^T emb + b_hid), h never materialized ----
    // Wave w reduces d in [64w, 64w+64); lane owns h columns {c..c+3, 256+c..256+c+3}.
    float z0p, z1p;
    {
        float4 ha, hb;
        if (w == 0) {           // bias folded into wave 0's partial
            ha = *(const float4*)(b_hid + c);
            hb = *(const float4*)(b_hid + 256 + c);
        } else {
            ha = (float4){0.f, 0.f, 0.f, 0.f};
            hb = (float4){0.f, 0.f, 0.f, 0.f};
        }
        #pragma unroll 8
        for (int i = 0; i < 64; ++i) {
            const int d = (w << 6) + i;
            const float s = emb[d];
            const float4 wa = *(const float4*)(W_hid + (size_t)d * HH + c);
            const float4 wb = *(const float4*)(W_hid + (size_t)d * HH + c + 256);
            ha.x = fmaf(s, wa.x, ha.x);
            ha.y = fmaf(s, wa.y, ha.y);
            ha.z = fmaf(s, wa.z, ha.z);
            ha.w = fmaf(s, wa.w, ha.w);
            hb.x = fmaf(s, wb.x, hb.x);
            hb.y = fmaf(s, wb.y, hb.y);
            hb.z = fmaf(s, wb.z, hb.z);
            hb.w = fmaf(s, wb.w, hb.w);
        }
        // dot local h partials with W_out rows (row j = floats 2j, 2j+1)
        const float4 o0a = *(const float4*)(W_out + 2 * c);            // rows c, c+1
        const float4 o0b = *(const float4*)(W_out + 2 * c + 4);        // rows c+2, c+3
        const float4 o1a = *(const float4*)(W_out + 2 * (c + 256));    // rows 256+c, 256+c+1
        const float4 o1b = *(const float4*)(W_out + 2 * (c + 256) + 4);
        z0p = ha.x * o0a.x + ha.y * o0a.z + ha.z * o0b.x + ha.w * o0b.z
            + hb.x * o1a.x + hb.y * o1a.z + hb.z * o1b.x + hb.w * o1b.z;
        z1p = ha.x * o0a.y + ha.y * o0a.w + ha.z * o0b.y + ha.w * o0b.w
            + hb.x * o1a.y + hb.y * o1a.w + hb.z * o1b.y + hb.w * o1b.w;
    }

    // ---- block reduce z0p, z1p across 256 threads (4 waves) ----
    for (int off = 32; off > 0; off >>= 1) {
        z0p += __shfl_down(z0p, off, 64);
        z1p += __shfl_down(z1p, off, 64);
    }
    if (l == 0) { red0[w] = z0p; red1[w] = z1p; }
    __syncthreads();

    if (t == 0) {
        float z0 = b_out[0] + red0[0] + red0[1] + red0[2] + red0[3];
        float z1 = b_out[1] + red1[0] + red1[1] + red1[2] + red1[3];
        // probs = softmax(z)
        float m  = fmaxf(z0, z1);
        float e0 = expf(z0 - m), e1 = expf(z1 - m);
        float inv = 1.0f / (e0 + e1);
        float p0 = e0 * inv, p1 = e1 * inv;
        probs_out[2 * g + 0] = p0;
        probs_out[2 * g + 1] = p1;
        // loss term = -(log_softmax(probs)[label]) = lse(probs) - probs[label]
        float mp  = fmaxf(p0, p1);
        float lse = mp + logf(expf(p0 - mp) + expf(p1 - mp));
        float pl  = (label[g] == 0) ? p0 : p1;
        loss_ws[g] = lse - pl;
    }
}

// Deterministic single-block sum of the 256 per-graph loss terms.
__global__ __launch_bounds__(256) void loss_reduce_kernel(
    const float* __restrict__ loss_ws, float* __restrict__ out)
{
    __shared__ float red[4];
    int t = threadIdx.x;
    float v = loss_ws[t];
    for (int off = 32; off > 0; off >>= 1) v += __shfl_down(v, off, 64);
    if ((t & 63) == 0) red[t >> 6] = v;
    __syncthreads();
    if (t == 0) out[0] = red[0] + red[1] + red[2] + red[3];
}

extern "C" void kernel_launch(void* const* d_in, const int* in_sizes, int n_in,
                              void* d_out, int out_size, void* d_ws, size_t ws_size,
                              hipStream_t stream) {
    const float* node_fea  = (const float*)d_in[0];
    const float* masks     = (const float*)d_in[1];
    const int*   node_type = (const int*)  d_in[2];
    const int*   g_node_id = (const int*)  d_in[3];
    const int*   label     = (const int*)  d_in[4];
    const float* W_emb     = (const float*)d_in[5];
    const float* b_emb     = (const float*)d_in[6];
    const float* W_hid     = (const float*)d_in[7];
    const float* b_hid     = (const float*)d_in[8];
    const float* W_out     = (const float*)d_in[9];
    const float* b_out     = (const float*)d_in[10];

    float* out = (float*)d_out;  // [G*2 probs][1 loss] = 513 floats
    float* ws  = (float*)d_ws;   // >= G floats of scratch

    fused_graph_kernel<<<GG, 256, 0, stream>>>(
        node_fea, masks, node_type, g_node_id, label,
        W_emb, b_emb, W_hid, b_hid, W_out, b_out,
        out, ws);

    loss_reduce_kernel<<<1, 256, 0, stream>>>(ws, out + GG * 2);
}